// Round 6
// baseline (344.391 us; speedup 1.0000x reference)
//
#include <hip/hip_runtime.h>
#include <hip/hip_bf16.h>
#include <math.h>

#define B_ 64
#define T_ 512
#define D_ 1024
#define M_ (B_*T_)   // 32768 rows of x flattened [B*T, D]

typedef unsigned short u16;
typedef __attribute__((ext_vector_type(8))) _Float16 f16x8;  // 8 fp16 in 4 VGPRs
typedef __attribute__((ext_vector_type(4))) float f32x4;

// fp32 -> fp16 RNE, bit pattern
__device__ __forceinline__ u16 f2h(float f) {
  union { _Float16 h; u16 u; } v;
  v.h = (_Float16)f;
  return v.u;
}

__device__ __forceinline__ float h2f(u16 u) {
  union { u16 u; _Float16 h; } v;
  v.u = u;
  return (float)v.h;
}

__device__ __forceinline__ float fast_tanh(float x) {
  // tanh(x) = 1 - 2/(exp(2x)+1); saturates correctly at +/-inf of expf
  return 1.0f - 2.0f / (__expf(2.0f * x) + 1.0f);
}

// async global->LDS, 16B per lane; LDS dest = wave-uniform base + lane*16
__device__ __forceinline__ void gll16(const void* g, void* l) {
  __builtin_amdgcn_global_load_lds(
      (const __attribute__((address_space(1))) unsigned int*)g,
      (__attribute__((address_space(3))) unsigned int*)l, 16, 0, 0);
}

// ---------------- K0a: convert x fp32 -> fp16 ----------------
__global__ __launch_bounds__(256) void cvt_x_kernel(const float4* __restrict__ x,
                                                    ushort4* __restrict__ xh, int n4) {
  int i = blockIdx.x * 256 + threadIdx.x;
  if (i < n4) {
    float4 v = x[i];
    ushort4 o;
    o.x = f2h(v.x); o.y = f2h(v.y); o.z = f2h(v.z); o.w = f2h(v.w);
    xh[i] = o;
  }
}

// ---------------- K0b: W [k,n] -> Wt [n,k] fp16 (LDS-tiled transpose) ----------------
__global__ __launch_bounds__(1024) void cvt_wt_kernel(const float* __restrict__ W,
                                                      u16* __restrict__ Wt) {
  __shared__ float tile[32][33];
  int tx = threadIdx.x & 31, ty = threadIdx.x >> 5;
  int n0 = blockIdx.x * 32, k0 = blockIdx.y * 32;
  tile[ty][tx] = W[(k0 + ty) * D_ + n0 + tx];
  __syncthreads();
  Wt[(n0 + ty) * D_ + k0 + tx] = f2h(tile[tx][ty]);
}

// LDS swizzle: row r, 16B chunk of logical k-pos c stored at in-row position
// (c + (r>>1)) & 3. Staging: lds dest fixed (base+lane*16) so lane (pos p, row r)
// fetches global chunk (p - (r>>1)) & 3; read side adds the forward permutation.
// Banks 2-way aliased = free (m136). Verified: conflicts 0 in rounds 4-5.

// ---------------- core: 128x128 tile, wave tile 64x64, BK=32 ----------------
// (m103/m105: 128-square is the verified sweet spot; this exact core passed in r5 gemm2)
__device__ __forceinline__ void gemm_core128(const u16* __restrict__ Abase,
                                             const u16* __restrict__ Bbase, int K,
                                             u16* As, u16* Bs, int tid, f32x4 acc[4][4]) {
  const int wave = tid >> 6, lane = tid & 63;
  const int swz_c = ((lane & 3) - ((lane >> 3) & 3)) & 3;
  const int rin = lane >> 2;
  const u16* gA[2]; u16* lA[2];
  const u16* gB[2]; u16* lB[2];
#pragma unroll
  for (int j = 0; j < 2; j++) {
    int ci = wave * 2 + j;
    gA[j] = Abase + (long)(ci * 16 + rin) * K + swz_c * 8;
    lA[j] = As + ci * 512;
    gB[j] = Bbase + (long)(ci * 16 + rin) * K + swz_c * 8;
    lB[j] = Bs + ci * 512;
  }
  const int wrow = (wave >> 1) * 64, wcol = (wave & 1) * 64;
  const int lm = lane & 15, qd = lane >> 4;
  const int swz_r = ((qd + (lm >> 1)) & 3) * 8;
  const u16* ra = As + (wrow + lm) * 32 + swz_r;
  const u16* rb = Bs + (wcol + lm) * 32 + swz_r;

  for (int kt = 0; kt < K; kt += 32) {
#pragma unroll
    for (int j = 0; j < 2; j++) {
      gll16(gA[j], lA[j]); gA[j] += 32;
      gll16(gB[j], lB[j]); gB[j] += 32;
    }
    __syncthreads();
    f16x8 af[4], bfr[4];
#pragma unroll
    for (int i = 0; i < 4; i++) {
      af[i] = *(const f16x8*)(ra + i * 512);
      bfr[i] = *(const f16x8*)(rb + i * 512);
    }
#pragma unroll
    for (int mi = 0; mi < 4; mi++)
#pragma unroll
      for (int ni = 0; ni < 4; ni++)
        acc[mi][ni] = __builtin_amdgcn_mfma_f32_16x16x32_f16(af[mi], bfr[ni], acc[mi][ni], 0, 0, 0);
    __syncthreads();
  }
}

// ---------------- K1: xw = x @ W  (M=32768, N=1024, K=1024), out fp16 ----------------
// 2048 blocks (8/CU). XCD grouping: bx&7 = XCD; consecutive j share one 128-row
// A-stripe (8 n-tiles) -> A-stripe fetched into that XCD L2 once. wt (2 MB) L2-resident.
__global__ __launch_bounds__(256, 4) void gemm1_kernel(const u16* __restrict__ xh,
                                                       const u16* __restrict__ wt,
                                                       u16* __restrict__ xw) {
  __shared__ u16 As[128 * 32], Bs[128 * 32];
  f32x4 acc[4][4] = {};
  const int tid = threadIdx.x;
  const int bx = blockIdx.x;                 // 2048 blocks
  const int xcd = bx & 7, j = bx >> 3;       // j in [0,256)
  const int mt = xcd * 32 + (j >> 3);        // 256 m-tiles
  const int nt = j & 7;                      // 8 n-tiles
  const long m0 = (long)mt * 128;
  const long n0 = (long)nt * 128;
  gemm_core128(xh + m0 * D_, wt + n0 * D_, D_, As, Bs, tid, acc);

  const int wave = tid >> 6, lane = tid & 63;
  const int wrow = (wave >> 1) * 64, wcol = (wave & 1) * 64;
  const int lm = lane & 15, qd = lane >> 4;
#pragma unroll
  for (int mi = 0; mi < 4; mi++)
#pragma unroll
    for (int ni = 0; ni < 4; ni++) {
      long m = m0 + wrow + mi * 16 + qd * 4;   // C/D: row=(lane>>4)*4+reg
      long n = n0 + wcol + ni * 16 + lm;       //      col=lane&15
      u16* p = xw + m * D_ + n;
#pragma unroll
      for (int r = 0; r < 4; r++) p[(long)r * D_] = f2h(acc[mi][ni][r]);
    }
}

// ---------------- K2: eij 128x128 tile + fused tanh*cv reduction -> partial scores ----
// 1024 blocks (4/CU). XCD grouping: the 16 tiles of one batch share an XCD with
// consecutive dispatch order -> batch working set (2 MB) fits the 4 MiB XCD-L2.
// 8 partial planes: plane = st*2 + (wave&1) (waves sharing t-rows cover different
// 64-col s-halves -> distinct planes; race-free).
__global__ __launch_bounds__(256, 4) void gemm2_kernel(const u16* __restrict__ xw,
                                                       const u16* __restrict__ xh,
                                                       const float* __restrict__ bias,
                                                       const float* __restrict__ cv,
                                                       float* __restrict__ scores_part) {
  __shared__ u16 As[128 * 32], Bs[128 * 32];
  f32x4 acc[4][4] = {};
  const int bx = blockIdx.x;
  const int xcd = bx & 7, j = bx >> 3;       // j in [0,128)
  const int bb = xcd * 8 + (j >> 4);         // 64 batches, 8 per XCD
  const int tile = j & 15;                   // 16 tiles per batch, consecutive j
  const int tt = tile >> 2, st = tile & 3;
  const int tid = threadIdx.x;
  const long arow = (long)bb * T_ + tt * 128;
  const long brow = (long)bb * T_ + st * 128;
  gemm_core128(xw + arow * D_, xh + brow * D_, D_, As, Bs, tid, acc);

  const int wave = tid >> 6, lane = tid & 63;
  const int wrow = (wave >> 1) * 64, wcol = (wave & 1) * 64;
  const int lm = lane & 15, qd = lane >> 4;
  float cvv[4], bv[4];
#pragma unroll
  for (int ni = 0; ni < 4; ni++) {
    int s = st * 128 + wcol + ni * 16 + lm;
    cvv[ni] = cv[s];
    bv[ni] = bias[s];
  }
  const int plane = st * 2 + (wave & 1);
  float* dst = scores_part + plane * (B_ * T_) + bb * T_ + tt * 128;
#pragma unroll
  for (int mi = 0; mi < 4; mi++) {
#pragma unroll
    for (int r = 0; r < 4; r++) {
      float p = 0.f;
#pragma unroll
      for (int ni = 0; ni < 4; ni++) p += fast_tanh(acc[mi][ni][r] + bv[ni]) * cvv[ni];
      // sum across the 16 cols held by this quad's lanes (lm bits 0..3)
      p += __shfl_xor(p, 1); p += __shfl_xor(p, 2);
      p += __shfl_xor(p, 4); p += __shfl_xor(p, 8);
      if (lm == 0) dst[wrow + mi * 16 + qd * 4 + r] = p;   // unique (plane,b,t) owner
    }
  }
}

// ---------------- K3: masked softmax over T per batch (sums 8 partials) ----------
__global__ __launch_bounds__(512) void softmax_kernel(const float* __restrict__ sp,
                                                      const unsigned char* __restrict__ m8,
                                                      float* __restrict__ a_out) {
  const int b = blockIdx.x, t = threadIdx.x;   // 512 threads = 8 waves
  __shared__ int nonz;
  __shared__ float redm[8], reds[8];
  if (t == 0) nonz = 0;
  __syncthreads();
  // detect int32-vs-uint8 bool storage
  unsigned char c = m8[t * 4 + 1] | m8[t * 4 + 2] | m8[t * 4 + 3];
  if (c) atomicOr(&nonz, 1);
  __syncthreads();
  const bool is_i32 = (nonz == 0);
  const int idx = b * T_ + t;
  const bool valid = is_i32 ? (m8[(long)idx * 4] != 0) : (m8[idx] != 0);

  float val = 0.f;
#pragma unroll
  for (int pl = 0; pl < 8; pl++) val += sp[pl * (B_ * T_) + idx];
  if (!valid) val = -INFINITY;
  float m = val;
#pragma unroll
  for (int o = 32; o > 0; o >>= 1) m = fmaxf(m, __shfl_xor(m, o));
  const int wv = t >> 6, ln = t & 63;
  if (ln == 0) redm[wv] = m;
  __syncthreads();
  float rowmax = redm[0];
#pragma unroll
  for (int i = 1; i < 8; i++) rowmax = fmaxf(rowmax, redm[i]);

  float e = valid ? expf(val - rowmax) : 0.f;
  float ssum = e;
#pragma unroll
  for (int o = 32; o > 0; o >>= 1) ssum += __shfl_xor(ssum, o);
  if (ln == 0) reds[wv] = ssum;
  __syncthreads();
  float tot = 0.f;
#pragma unroll
  for (int i = 0; i < 8; i++) tot += reds[i];
  a_out[idx] = e / tot;
}

// ---------------- K4: out[b,d] = sum_t a[b,t] * xh[b,t,d]  (vectorized) -------
// grid (64,4) x 256 thr (4 waves). Lane covers 4 d's (ushort4, 8B/lane ->
// 512B/wave/row); wave w sums t in [w*128,(w+1)*128); LDS float4 reduce.
__global__ __launch_bounds__(256) void wsum_kernel(const u16* __restrict__ xh,
                                                   const float* __restrict__ a,
                                                   float* __restrict__ out) {
  __shared__ float4 lred[4][64];
  const int b = blockIdx.x, dq = blockIdx.y, tid = threadIdx.x;
  const int w = tid >> 6, lane = tid & 63;
  const int d0 = dq * 256 + lane * 4;
  const u16* xp = xh + (long)b * T_ * D_ + d0;
  const float* ap = a + b * T_;
  float4 acc = make_float4(0.f, 0.f, 0.f, 0.f);
  for (int i = 0; i < 128; i++) {
    int t = w * 128 + i;
    float av = ap[t];
    ushort4 xv = *(const ushort4*)(xp + (long)t * D_);
    acc.x += av * h2f(xv.x); acc.y += av * h2f(xv.y);
    acc.z += av * h2f(xv.z); acc.w += av * h2f(xv.w);
  }
  lred[w][lane] = acc;
  __syncthreads();
  if (w == 0) {
    float4 s0 = lred[0][lane], s1 = lred[1][lane], s2 = lred[2][lane], s3 = lred[3][lane];
    float4 s;
    s.x = s0.x + s1.x + s2.x + s3.x;
    s.y = s0.y + s1.y + s2.y + s3.y;
    s.z = s0.z + s1.z + s2.z + s3.z;
    s.w = s0.w + s1.w + s2.w + s3.w;
    *(float4*)(out + (long)b * D_ + d0) = s;
  }
}

extern "C" void kernel_launch(void* const* d_in, const int* in_sizes, int n_in,
                              void* d_out, int out_size, void* d_ws, size_t ws_size,
                              hipStream_t stream) {
  const float* x = (const float*)d_in[0];
  const unsigned char* mask = (const unsigned char*)d_in[1];
  const float* W = (const float*)d_in[2];
  const float* cv = (const float*)d_in[3];
  const float* bias = (const float*)d_in[4];

  float* out = (float*)d_out;                  // [B,D]
  float* a_out = out + (size_t)B_ * D_;        // [B,T]

  // workspace layout (130 MiB): scores_part (1 MiB, 8 planes) aliases wt (dead after gemm1)
  char* ws = (char*)d_ws;
  u16* xh = (u16*)(ws);                         // fp16 x    [M_, D_]  64 MiB
  u16* wt = (u16*)(ws + 67108864);              // fp16 W^T  [D_, D_]   2 MiB
  float* scores_part = (float*)(ws + 67108864); // fp32 [8][B_,T_] 1 MiB (aliases wt)
  u16* xw = (u16*)(ws + 69206016);              // fp16 x@W  [M_, D_]  64 MiB

  cvt_x_kernel<<<(M_ * D_ / 4 + 255) / 256, 256, 0, stream>>>((const float4*)x,
                                                              (ushort4*)xh, M_ * D_ / 4);
  cvt_wt_kernel<<<dim3(32, 32), 1024, 0, stream>>>(W, wt);
  gemm1_kernel<<<2048, 256, 0, stream>>>(xh, wt, xw);
  gemm2_kernel<<<1024, 256, 0, stream>>>(xw, xh, bias, cv, scores_part);
  softmax_kernel<<<B_, 512, 0, stream>>>(scores_part, mask, a_out);
  wsum_kernel<<<dim3(B_, 4), 256, 0, stream>>>(xh, a_out, out);
}

// Round 7
// 323.423 us; speedup vs baseline: 1.0648x; 1.0648x over previous
//
#include <hip/hip_runtime.h>
#include <hip/hip_bf16.h>
#include <math.h>

#define B_ 64
#define T_ 512
#define D_ 1024
#define M_ (B_*T_)   // 32768 rows of x flattened [B*T, D]

typedef unsigned short u16;
typedef __attribute__((ext_vector_type(8))) _Float16 f16x8;  // 8 fp16 in 4 VGPRs
typedef __attribute__((ext_vector_type(4))) float f32x4;

// fp32 -> fp16 RNE, bit pattern
__device__ __forceinline__ u16 f2h(float f) {
  union { _Float16 h; u16 u; } v;
  v.h = (_Float16)f;
  return v.u;
}

__device__ __forceinline__ float h2f(u16 u) {
  union { u16 u; _Float16 h; } v;
  v.u = u;
  return (float)v.h;
}

__device__ __forceinline__ float fast_tanh(float x) {
  // tanh(x) = 1 - 2/(exp(2x)+1); saturates correctly at +/-inf of expf
  return 1.0f - 2.0f / (__expf(2.0f * x) + 1.0f);
}

// async global->LDS, 16B per lane; LDS dest = wave-uniform base + lane*16
__device__ __forceinline__ void gll16(const void* g, void* l) {
  __builtin_amdgcn_global_load_lds(
      (const __attribute__((address_space(1))) unsigned int*)g,
      (__attribute__((address_space(3))) unsigned int*)l, 16, 0, 0);
}

// ---------------- K0: fused cvt — blocks <32768: x fp32->fp16; rest: W -> Wt ------
__global__ __launch_bounds__(256) void cvt_kernel(const float4* __restrict__ x,
                                                  ushort4* __restrict__ xh,
                                                  const float* __restrict__ W,
                                                  u16* __restrict__ wt) {
  __shared__ float tile[32][33];
  const int bid = blockIdx.x;
  if (bid < 32768) {
    int i = bid * 256 + threadIdx.x;
    float4 v = x[i];
    ushort4 o;
    o.x = f2h(v.x); o.y = f2h(v.y); o.z = f2h(v.z); o.w = f2h(v.w);
    xh[i] = o;
  } else {
    const int tb = bid - 32768;                 // 1024 transpose tiles
    const int n0 = (tb & 31) * 32, k0 = (tb >> 5) * 32;
    const int tx = threadIdx.x & 31, ty = threadIdx.x >> 5;  // ty 0..7
#pragma unroll
    for (int ph = 0; ph < 4; ph++)
      tile[ty + ph * 8][tx] = W[(k0 + ty + ph * 8) * D_ + n0 + tx];
    __syncthreads();
#pragma unroll
    for (int ph = 0; ph < 4; ph++)
      wt[(long)(n0 + ty + ph * 8) * D_ + k0 + tx] = f2h(tile[tx][ty + ph * 8]);
  }
}

// ---------------- K1: xw = x @ W  — 256x128 tile, BK=64, 1024 blocks ----------------
// BK=64 swizzle: row r (64 elems = 8 chunks of 16B), logical chunk c stored at
// position (c + (r>>1)) & 7. Staging lane (p=lane&7, rl=lane>>3) of group g
// (rows g*8..g*8+7) fetches global chunk (p - (r>>1)) & 7. Per-16-lane phase the
// read hits 8 distinct 4-bank groups, 2 lanes each -> conflict-free (as BK=32 was).
// Halves barrier-iterations vs BK=32 (16 vs 32) at the same 2 blocks/CU (48 KB LDS).
__global__ __launch_bounds__(256, 2) void gemm1_kernel(const u16* __restrict__ xh,
                                                       const u16* __restrict__ wt,
                                                       u16* __restrict__ xw) {
  __shared__ u16 As[256 * 64];   // 32 KB
  __shared__ u16 Bs[128 * 64];   // 16 KB
  f32x4 acc[8][4] = {};
  const int tid = threadIdx.x;
  const int bx = blockIdx.x;                 // 1024 blocks
  const int xcd = bx & 7, j = bx >> 3;       // j in [0,128)
  const int mt = xcd * 16 + (j >> 3);        // 128 m-tiles of 256 rows
  const int nt = j & 7;                      // 8 n-tiles of 128
  const long m0 = (long)mt * 256;
  const long n0 = (long)nt * 128;
  const u16* Abase = xh + m0 * D_;
  const u16* Bbase = wt + n0 * D_;

  const int wave = tid >> 6, lane = tid & 63;
  const int p = lane & 7, rl = lane >> 3;    // staging coords within 8-row group

  const u16* gA[8]; u16* lA[8];
#pragma unroll
  for (int i = 0; i < 8; i++) {              // A: 32 groups, 8 per wave
    int g = wave * 8 + i;
    int r = g * 8 + rl;
    int c = (p - (r >> 1)) & 7;
    gA[i] = Abase + (long)r * D_ + c * 8;
    lA[i] = As + g * 512;
  }
  const u16* gB[4]; u16* lB[4];
#pragma unroll
  for (int i = 0; i < 4; i++) {              // B: 16 groups, 4 per wave
    int g = wave * 4 + i;
    int r = g * 8 + rl;
    int c = (p - (r >> 1)) & 7;
    gB[i] = Bbase + (long)r * D_ + c * 8;
    lB[i] = Bs + g * 512;
  }

  const int wrow = (wave >> 1) * 128, wcol = (wave & 1) * 64;
  const int lm = lane & 15, qd = lane >> 4;
  const u16* ra = As + (wrow + lm) * 64;
  const u16* rb = Bs + (wcol + lm) * 64;
  // read-side chunk position: p' = (kk*4 + qd + (m>>1)) & 7; m-tile terms vanish mod 8
  const int pk0 = ((qd + (lm >> 1)) & 7) * 8;
  const int pk1 = ((qd + 4 + (lm >> 1)) & 7) * 8;

  for (int kt = 0; kt < D_; kt += 64) {
#pragma unroll
    for (int i = 0; i < 8; i++) { gll16(gA[i], lA[i]); gA[i] += 64; }
#pragma unroll
    for (int i = 0; i < 4; i++) { gll16(gB[i], lB[i]); gB[i] += 64; }
    __syncthreads();
#pragma unroll
    for (int kk = 0; kk < 2; kk++) {
      const int pk = kk ? pk1 : pk0;
      f16x8 af[8], bfr[4];
#pragma unroll
      for (int i = 0; i < 8; i++) af[i] = *(const f16x8*)(ra + i * 16 * 64 + pk);
#pragma unroll
      for (int i = 0; i < 4; i++) bfr[i] = *(const f16x8*)(rb + i * 16 * 64 + pk);
#pragma unroll
      for (int mi = 0; mi < 8; mi++)
#pragma unroll
        for (int ni = 0; ni < 4; ni++)
          acc[mi][ni] = __builtin_amdgcn_mfma_f32_16x16x32_f16(af[mi], bfr[ni], acc[mi][ni], 0, 0, 0);
    }
    __syncthreads();
  }

  const int lm2 = lane & 15, qd2 = lane >> 4;
#pragma unroll
  for (int mi = 0; mi < 8; mi++)
#pragma unroll
    for (int ni = 0; ni < 4; ni++) {
      long m = m0 + wrow + mi * 16 + qd2 * 4;  // C/D: row=(lane>>4)*4+reg
      long n = n0 + wcol + ni * 16 + lm2;      //      col=lane&15
      u16* ptr = xw + m * D_ + n;
#pragma unroll
      for (int r = 0; r < 4; r++) ptr[(long)r * D_] = f2h(acc[mi][ni][r]);
    }
}

// ---------------- core: 128x128 tile, wave tile 64x64, BK=32 (gemm2, verified) -------
// BK=32 swizzle: position (c + (r>>1)) & 3; conflicts measured 0 (r4-r6).
__device__ __forceinline__ void gemm_core128(const u16* __restrict__ Abase,
                                             const u16* __restrict__ Bbase, int K,
                                             u16* As, u16* Bs, int tid, f32x4 acc[4][4]) {
  const int wave = tid >> 6, lane = tid & 63;
  const int swz_c = ((lane & 3) - ((lane >> 3) & 3)) & 3;
  const int rin = lane >> 2;
  const u16* gA[2]; u16* lA[2];
  const u16* gB[2]; u16* lB[2];
#pragma unroll
  for (int j = 0; j < 2; j++) {
    int ci = wave * 2 + j;
    gA[j] = Abase + (long)(ci * 16 + rin) * K + swz_c * 8;
    lA[j] = As + ci * 512;
    gB[j] = Bbase + (long)(ci * 16 + rin) * K + swz_c * 8;
    lB[j] = Bs + ci * 512;
  }
  const int wrow = (wave >> 1) * 64, wcol = (wave & 1) * 64;
  const int lm = lane & 15, qd = lane >> 4;
  const int swz_r = ((qd + (lm >> 1)) & 3) * 8;
  const u16* ra = As + (wrow + lm) * 32 + swz_r;
  const u16* rb = Bs + (wcol + lm) * 32 + swz_r;

  for (int kt = 0; kt < K; kt += 32) {
#pragma unroll
    for (int j = 0; j < 2; j++) {
      gll16(gA[j], lA[j]); gA[j] += 32;
      gll16(gB[j], lB[j]); gB[j] += 32;
    }
    __syncthreads();
    f16x8 af[4], bfr[4];
#pragma unroll
    for (int i = 0; i < 4; i++) {
      af[i] = *(const f16x8*)(ra + i * 512);
      bfr[i] = *(const f16x8*)(rb + i * 512);
    }
#pragma unroll
    for (int mi = 0; mi < 4; mi++)
#pragma unroll
      for (int ni = 0; ni < 4; ni++)
        acc[mi][ni] = __builtin_amdgcn_mfma_f32_16x16x32_f16(af[mi], bfr[ni], acc[mi][ni], 0, 0, 0);
    __syncthreads();
  }
}

// ---------------- K2: eij 128x128 tile + fused tanh*cv reduction -> partial scores ----
// 1024 blocks (4/CU). XCD grouping: 16 tiles of one batch share an XCD -> batch
// working set (2 MB) fits 4 MiB XCD-L2. 8 planes: plane = st*2 + (wave&1) (race-free).
__global__ __launch_bounds__(256, 4) void gemm2_kernel(const u16* __restrict__ xw,
                                                       const u16* __restrict__ xh,
                                                       const float* __restrict__ bias,
                                                       const float* __restrict__ cv,
                                                       float* __restrict__ scores_part) {
  __shared__ u16 As[128 * 32], Bs[128 * 32];
  f32x4 acc[4][4] = {};
  const int bx = blockIdx.x;
  const int xcd = bx & 7, j = bx >> 3;       // j in [0,128)
  const int bb = xcd * 8 + (j >> 4);         // 64 batches, 8 per XCD
  const int tile = j & 15;                   // 16 tiles per batch, consecutive j
  const int tt = tile >> 2, st = tile & 3;
  const int tid = threadIdx.x;
  const long arow = (long)bb * T_ + tt * 128;
  const long brow = (long)bb * T_ + st * 128;
  gemm_core128(xw + arow * D_, xh + brow * D_, D_, As, Bs, tid, acc);

  const int wave = tid >> 6, lane = tid & 63;
  const int wrow = (wave >> 1) * 64, wcol = (wave & 1) * 64;
  const int lm = lane & 15, qd = lane >> 4;
  float cvv[4], bv[4];
#pragma unroll
  for (int ni = 0; ni < 4; ni++) {
    int s = st * 128 + wcol + ni * 16 + lm;
    cvv[ni] = cv[s];
    bv[ni] = bias[s];
  }
  const int plane = st * 2 + (wave & 1);
  float* dst = scores_part + plane * (B_ * T_) + bb * T_ + tt * 128;
#pragma unroll
  for (int mi = 0; mi < 4; mi++) {
#pragma unroll
    for (int r = 0; r < 4; r++) {
      float p = 0.f;
#pragma unroll
      for (int ni = 0; ni < 4; ni++) p += fast_tanh(acc[mi][ni][r] + bv[ni]) * cvv[ni];
      p += __shfl_xor(p, 1); p += __shfl_xor(p, 2);
      p += __shfl_xor(p, 4); p += __shfl_xor(p, 8);
      if (lm == 0) dst[wrow + mi * 16 + qd * 4 + r] = p;   // unique (plane,b,t) owner
    }
  }
}

// ---------------- K3: fused masked-softmax + weighted-sum ----------------
// grid (64,4) x 256 thr. Each block: softmax of batch b (redundant x4, cheap),
// a_out written by dq==0 blocks only; then wsum of its 256-d slice (atomic-free).
__global__ __launch_bounds__(256) void sm_wsum_kernel(const float* __restrict__ sp,
                                                      const unsigned char* __restrict__ m8,
                                                      const u16* __restrict__ xh,
                                                      float* __restrict__ a_out,
                                                      float* __restrict__ out) {
  __shared__ float a_sh[512];
  __shared__ float red[8];
  __shared__ int nonz;
  __shared__ float4 lred[4][64];
  const int b = blockIdx.x, dq = blockIdx.y, tid = threadIdx.x;
  const int w = tid >> 6, ln = tid & 63;
  if (tid == 0) nonz = 0;
  __syncthreads();
  // detect int32-vs-uint8 bool storage from first 512 mask words
  {
    unsigned char c = m8[tid * 4 + 1] | m8[tid * 4 + 2] | m8[tid * 4 + 3] |
                      m8[(tid + 256) * 4 + 1] | m8[(tid + 256) * 4 + 2] | m8[(tid + 256) * 4 + 3];
    if (c) atomicOr(&nonz, 1);
  }
  __syncthreads();
  const bool is_i32 = (nonz == 0);
  float v[2]; bool valid[2];
#pragma unroll
  for (int h = 0; h < 2; h++) {
    int t = tid + h * 256;
    int idx = b * T_ + t;
    valid[h] = is_i32 ? (m8[(long)idx * 4] != 0) : (m8[idx] != 0);
    float s = 0.f;
#pragma unroll
    for (int pl = 0; pl < 8; pl++) s += sp[pl * (B_ * T_) + idx];
    v[h] = valid[h] ? s : -INFINITY;
  }
  float m = fmaxf(v[0], v[1]);
#pragma unroll
  for (int o = 32; o > 0; o >>= 1) m = fmaxf(m, __shfl_xor(m, o));
  if (ln == 0) red[w] = m;
  __syncthreads();
  const float rowmax = fmaxf(fmaxf(red[0], red[1]), fmaxf(red[2], red[3]));
  float e0 = valid[0] ? expf(v[0] - rowmax) : 0.f;
  float e1 = valid[1] ? expf(v[1] - rowmax) : 0.f;
  float ss = e0 + e1;
#pragma unroll
  for (int o = 32; o > 0; o >>= 1) ss += __shfl_xor(ss, o);
  if (ln == 0) red[4 + w] = ss;
  __syncthreads();
  const float tot = red[4] + red[5] + red[6] + red[7];
  const float a0 = e0 / tot, a1 = e1 / tot;
  a_sh[tid] = a0; a_sh[tid + 256] = a1;
  if (dq == 0) {
    a_out[b * T_ + tid] = a0;
    a_out[b * T_ + tid + 256] = a1;
  }
  __syncthreads();
  // weighted sum: lane covers 4 d's; wave w sums t in [w*128,(w+1)*128)
  const int d0 = dq * 256 + ln * 4;
  const u16* xp = xh + (long)b * T_ * D_ + d0;
  float4 acc = make_float4(0.f, 0.f, 0.f, 0.f);
  for (int i = 0; i < 128; i++) {
    int t = w * 128 + i;
    float av = a_sh[t];
    ushort4 xv = *(const ushort4*)(xp + (long)t * D_);
    acc.x += av * h2f(xv.x); acc.y += av * h2f(xv.y);
    acc.z += av * h2f(xv.z); acc.w += av * h2f(xv.w);
  }
  lred[w][ln] = acc;
  __syncthreads();
  if (w == 0) {
    float4 s0 = lred[0][ln], s1 = lred[1][ln], s2 = lred[2][ln], s3 = lred[3][ln];
    float4 s;
    s.x = s0.x + s1.x + s2.x + s3.x;
    s.y = s0.y + s1.y + s2.y + s3.y;
    s.z = s0.z + s1.z + s2.z + s3.z;
    s.w = s0.w + s1.w + s2.w + s3.w;
    *(float4*)(out + (long)b * D_ + d0) = s;
  }
}

extern "C" void kernel_launch(void* const* d_in, const int* in_sizes, int n_in,
                              void* d_out, int out_size, void* d_ws, size_t ws_size,
                              hipStream_t stream) {
  const float* x = (const float*)d_in[0];
  const unsigned char* mask = (const unsigned char*)d_in[1];
  const float* W = (const float*)d_in[2];
  const float* cv = (const float*)d_in[3];
  const float* bias = (const float*)d_in[4];

  float* out = (float*)d_out;                  // [B,D]
  float* a_out = out + (size_t)B_ * D_;        // [B,T]

  // workspace layout (130 MiB): scores_part (1 MiB, 8 planes) aliases wt (dead after gemm1)
  char* ws = (char*)d_ws;
  u16* xh = (u16*)(ws);                         // fp16 x    [M_, D_]  64 MiB
  u16* wt = (u16*)(ws + 67108864);              // fp16 W^T  [D_, D_]   2 MiB
  float* scores_part = (float*)(ws + 67108864); // fp32 [8][B_,T_] 1 MiB (aliases wt)
  u16* xw = (u16*)(ws + 69206016);              // fp16 x@W  [M_, D_]  64 MiB

  cvt_kernel<<<32768 + 1024, 256, 0, stream>>>((const float4*)x, (ushort4*)xh, W, wt);
  gemm1_kernel<<<1024, 256, 0, stream>>>(xh, wt, xw);
  gemm2_kernel<<<1024, 256, 0, stream>>>(xw, xh, bias, cv, scores_part);
  sm_wsum_kernel<<<dim3(B_, 4), 256, 0, stream>>>(scores_part, mask, xh, a_out, out);
}